// Round 9
// baseline (328.468 us; speedup 1.0000x reference)
//
#include <hip/hip_runtime.h>

#define LOG100 4.605170185988091f
#define LOG2E  1.4426950408889634f

typedef _Float16 half8 __attribute__((ext_vector_type(8)));
typedef float f32x4 __attribute__((ext_vector_type(4)));

// ---- bias pack pre-kernel: biasP[h][kv/2][q] = fp16pair(bias[h][q][2kp], bias[h][q][2kp+1]) * LOG2E
__global__ __launch_bounds__(256) void bias_pack(const float* __restrict__ bias,
                                                 unsigned* __restrict__ biasP) {
  __shared__ float tile[32][33];
  const int head = blockIdx.z;
  const int m0 = blockIdx.x * 32;  // kv
  const int n0 = blockIdx.y * 32;  // q
  const float* src = bias + head * 65536;
  unsigned* dst = biasP + head * 32768;
  const int tx = threadIdx.x, ty = threadIdx.y;  // (32,8)
#pragma unroll
  for (int i = ty; i < 32; i += 8) tile[i][tx] = src[(n0 + i) * 256 + m0 + tx];
  __syncthreads();
#pragma unroll
  for (int j = ty; j < 16; j += 8) {
    const float lo = tile[tx][2 * j] * LOG2E;
    const float hi = tile[tx][2 * j + 1] * LOG2E;
    dst[(m0 / 2 + j) * 256 + n0 + tx] =
        __builtin_bit_cast(unsigned, __builtin_amdgcn_cvt_pkrtz(lo, hi));
  }
}

// ---- main attention kernel -------------------------------------------------
// Persistent-ish: grid 256 blocks x 1024 thr (16 waves); block g owns head g&7
// and processes 8 tiles b = (g>>3)*8 + t. K/V of tile t+1 are prefetched into
// registers before tile t's compute barrier -> HBM stays busy during compute.
// 16x16x32 MFMA core (r7, verified); permuted-k PV (no cross-lane P exchange).
template <bool USE_BT>
__global__ __launch_bounds__(1024, 4) void attn_kernel(
    const float* __restrict__ q, const float* __restrict__ k, const float* __restrict__ v,
    const float* __restrict__ logit_scale, const float* __restrict__ bias,
    const unsigned* __restrict__ biasP, float* __restrict__ out) {
  __shared__ __align__(16) char smem[65536];
  char* KnB = smem;          // Kn: [256 kv][64 d] fp16, 128B rows, byte ^= (row&7)<<4
  char* VtB = smem + 32768;  // Vt: [64 d][256 kv'] fp16 (kv' permuted), 512B rows, byte ^= (d&31)<<4

  const int tid = threadIdx.x;
  const int wv = tid >> 6;    // 0..15
  const int lane = tid & 63;
  const int q16 = lane & 15;  // q col within wave tile
  const int g4 = lane >> 4;   // 0..3 lane group
  const int gb = blockIdx.x;  // 0..255
  const int head = gb & 7;
  const int bgrp = gb >> 3;   // 0..31

  const float scale2 = __expf(fminf(logit_scale[head], LOG100)) * LOG2E;
  const int qglob = wv * 16 + q16;

  const unsigned* bP = USE_BT ? (biasP + head * 32768 + qglob) : nullptr;
  const float* bF = USE_BT ? nullptr : (bias + head * 65536 + qglob * 256);

  // staging index precompute
  const int krow_in = tid >> 4;  // 0..63 (K convert: 4 iters x 64 rows)
  const int kseg = tid & 15;     // 16 segs x 4 floats

  // ---- prefetch registers: K/V of the upcoming tile (32 VGPRs held) ----
  float4 kReg[4], vReg[4];
  {
    const long base0 = ((long)((bgrp * 8) * 8 + head)) * (256 * 64);
    const float* kp = k + base0;
    const float* vp = v + base0;
#pragma unroll
    for (int it = 0; it < 4; ++it) {
      kReg[it] = *(const float4*)(kp + (it * 64 + krow_in) * 64 + kseg * 4);
      vReg[it] = *(const float4*)(vp + ((wv * 4 + it) * 4 + g4) * 64 + q16 * 4);
    }
  }

#pragma unroll 1
  for (int t = 0; t < 8; ++t) {
    const int b = bgrp * 8 + t;
    const long base = ((long)(b * 8 + head)) * (256 * 64);
    const float* qp = q + base;

    // ---- Q raw loads first (latency hides under K/V converts below) ----
    float4 qraw[4];  // qraw[2*dk+x] = Q[qglob][dk*32 + g4*8 + 4x ..]
#pragma unroll
    for (int dk = 0; dk < 2; ++dk) {
      qraw[2 * dk] = *(const float4*)(qp + qglob * 64 + dk * 32 + g4 * 8);
      qraw[2 * dk + 1] = *(const float4*)(qp + qglob * 64 + dk * 32 + g4 * 8 + 4);
    }

    // ---- K convert: kReg -> L2-normalize -> fp16 -> LDS (swizzled) ----
#pragma unroll
    for (int it = 0; it < 4; ++it) {
      const int row = it * 64 + krow_in;
      const float4 a = kReg[it];
      float ss = a.x * a.x + a.y * a.y + a.z * a.z + a.w * a.w;
      ss += __shfl_xor(ss, 1);
      ss += __shfl_xor(ss, 2);
      ss += __shfl_xor(ss, 4);
      ss += __shfl_xor(ss, 8);
      const float inv = rsqrtf(fmaxf(ss, 1e-24f));
      union { _Float16 hh[4]; uint2 u; } pk4;
      pk4.hh[0] = (_Float16)(a.x * inv);
      pk4.hh[1] = (_Float16)(a.y * inv);
      pk4.hh[2] = (_Float16)(a.z * inv);
      pk4.hh[3] = (_Float16)(a.w * inv);
      *(uint2*)(KnB + row * 128 + ((kseg * 8) ^ ((row & 7) << 4))) = pk4.u;
    }

    // ---- V convert: vReg -> 4x4 lane transpose -> fp16 -> LDS (permuted cols) ----
#pragma unroll
    for (int it = 0; it < 4; ++it) {
      const int kv0 = (wv * 4 + it) * 4;  // 0..252
      float4 a = vReg[it];
      const int r = g4;
      float e1 = (r & 1) ? a.x : a.y;
      float g1 = __shfl_xor(e1, 16);
      float e2 = (r & 1) ? a.z : a.w;
      float g2 = __shfl_xor(e2, 16);
      if (r & 1) { a.x = g1; a.z = g2; } else { a.y = g1; a.w = g2; }
      float e3 = (r & 2) ? a.x : a.z;
      float g3 = __shfl_xor(e3, 32);
      float e4 = (r & 2) ? a.y : a.w;
      float g4v = __shfl_xor(e4, 32);
      if (r & 2) { a.x = g3; a.y = g4v; } else { a.z = g3; a.w = g4v; }
      // lane holds V[kv0+0..3][d], d = 4*q16 + r
      const int d = 4 * q16 + r;
      const int col0 = (kv0 & ~31) + (((kv0 >> 2) & 3) << 3) + (((kv0 >> 4) & 1) << 2);
      union { _Float16 hh[4]; uint2 u; } pk4;
      pk4.hh[0] = (_Float16)a.x;
      pk4.hh[1] = (_Float16)a.y;
      pk4.hh[2] = (_Float16)a.z;
      pk4.hh[3] = (_Float16)a.w;
      *(uint2*)(VtB + d * 512 + ((col0 * 2) ^ ((d & 31) << 4))) = pk4.u;
    }

    // ---- finish Q: normalize into B-frags ----
    half8 qfrag[2];
    {
      float ssq = 0.f;
#pragma unroll
      for (int i = 0; i < 4; ++i) {
        const float4 x = qraw[i];
        ssq += x.x * x.x + x.y * x.y + x.z * x.z + x.w * x.w;
      }
      ssq += __shfl_xor(ssq, 16);
      ssq += __shfl_xor(ssq, 32);
      const float qinv = rsqrtf(fmaxf(ssq, 1e-24f));
#pragma unroll
      for (int dk = 0; dk < 2; ++dk) {
        const float4 x0 = qraw[2 * dk];
        const float4 x1 = qraw[2 * dk + 1];
        qfrag[dk][0] = (_Float16)(x0.x * qinv);
        qfrag[dk][1] = (_Float16)(x0.y * qinv);
        qfrag[dk][2] = (_Float16)(x0.z * qinv);
        qfrag[dk][3] = (_Float16)(x0.w * qinv);
        qfrag[dk][4] = (_Float16)(x1.x * qinv);
        qfrag[dk][5] = (_Float16)(x1.y * qinv);
        qfrag[dk][6] = (_Float16)(x1.z * qinv);
        qfrag[dk][7] = (_Float16)(x1.w * qinv);
      }
    }

    // ---- issue NEXT tile's K/V loads (in flight across the whole compute phase) ----
    {
      const int bn = bgrp * 8 + (t < 7 ? t + 1 : 7);  // clamped; t=7 reload unused
      const long baseN = ((long)(bn * 8 + head)) * (256 * 64);
      const float* kpN = k + baseN;
      const float* vpN = v + baseN;
#pragma unroll
      for (int it = 0; it < 4; ++it) {
        kReg[it] = *(const float4*)(kpN + (it * 64 + krow_in) * 64 + kseg * 4);
        vReg[it] = *(const float4*)(vpN + ((wv * 4 + it) * 4 + g4) * 64 + q16 * 4);
      }
    }

    __syncthreads();

    // ---- kv loop: 8 chunks of 32 ----
    f32x4 o0 = {}, o1 = {}, o2 = {}, o3 = {};  // O^T: o{dt} -> q = q16, d = 16*dt + 4*g4 + reg
    float m = -1.0e30f, lsum = 0.f;  // log2 domain; lsum = per-lane partial

    for (int c = 0; c < 8; ++c) {
      // bias preload: pairs covering kv = c*32 + kvt*16 + g4*4 + 2p + {0,1}
      unsigned bw[4];
      float bvf[8];
      if (USE_BT) {
#pragma unroll
        for (int kvt = 0; kvt < 2; ++kvt)
#pragma unroll
          for (int p = 0; p < 2; ++p) bw[kvt * 2 + p] = bP[(c * 16 + kvt * 8 + g4 * 2 + p) * 256];
      } else {
#pragma unroll
        for (int i = 0; i < 8; ++i)
          bvf[i] = bF[c * 32 + (i >> 2) * 16 + g4 * 4 + (i & 3)] * LOG2E;
      }

      // QK^T (16x16x32): A = K rows (kv = c*32 + 16*kvt + q16), B = qfrag
      const int rk0 = c * 32 + q16;
      const char* kb0 = KnB + rk0 * 128;
      const char* kb1 = KnB + (rk0 + 16) * 128;
      const int sw = (rk0 & 7) << 4;
      f32x4 s0 = {}, s1 = {};
#pragma unroll
      for (int dk = 0; dk < 2; ++dk) {
        const half8 kf0 = *(const half8*)(kb0 + ((g4 * 16 + dk * 64) ^ sw));
        s0 = __builtin_amdgcn_mfma_f32_16x16x32_f16(kf0, qfrag[dk], s0, 0, 0, 0);
        const half8 kf1 = *(const half8*)(kb1 + ((g4 * 16 + dk * 64) ^ sw));
        s1 = __builtin_amdgcn_mfma_f32_16x16x32_f16(kf1, qfrag[dk], s1, 0, 0, 0);
      }

      // scale + bias (log2 domain): sv[kvt*4+reg]
      float sv[8];
      if (USE_BT) {
#pragma unroll
        for (int kvt = 0; kvt < 2; ++kvt)
#pragma unroll
          for (int p = 0; p < 2; ++p) {
            const _Float16* hp = (const _Float16*)&bw[kvt * 2 + p];
            const int i = kvt * 4 + 2 * p;
            const float* sp = (kvt == 0) ? (const float*)&s0 : (const float*)&s1;
            sv[i] = fmaf(sp[2 * p], scale2, (float)hp[0]);
            sv[i + 1] = fmaf(sp[2 * p + 1], scale2, (float)hp[1]);
          }
      } else {
#pragma unroll
        for (int i = 0; i < 4; ++i) sv[i] = fmaf(s0[i], scale2, bvf[i]);
#pragma unroll
        for (int i = 0; i < 4; ++i) sv[4 + i] = fmaf(s1[i], scale2, bvf[4 + i]);
      }

      // local tree max; cross-lane reduce only when rescale triggers
      float m4[4];
#pragma unroll
      for (int i = 0; i < 4; ++i) m4[i] = fmaxf(sv[2 * i], sv[2 * i + 1]);
      const float mxl = fmaxf(fmaxf(m4[0], m4[1]), fmaxf(m4[2], m4[3]));
      if (__any(mxl > m + 8.0f)) {
        float mx = fmaxf(mxl, __shfl_xor(mxl, 16));
        mx = fmaxf(mx, __shfl_xor(mx, 32));
        const float mnew = fmaxf(m, mx);
        const float corr = exp2f(m - mnew);
        lsum *= corr;
#pragma unroll
        for (int i = 0; i < 4; ++i) {
          o0[i] *= corr; o1[i] *= corr; o2[i] *= corr; o3[i] *= corr;
        }
        m = mnew;
      }

      // exp2 + per-lane psum partial (no cross-lane here)
#pragma unroll
      for (int i = 0; i < 8; ++i) sv[i] = exp2f(sv[i] - m);
      float a4[4];
#pragma unroll
      for (int i = 0; i < 4; ++i) a4[i] = sv[2 * i] + sv[2 * i + 1];
      lsum += (a4[0] + a4[1]) + (a4[2] + a4[3]);

      // pack P -> PV B-frag (permuted-k: slot j holds kv = c*32 + 16*(j>>2) + 4*g4 + (j&3))
      union { unsigned u[4]; half8 hh; } pf;
      pf.u[0] = __builtin_bit_cast(unsigned, __builtin_amdgcn_cvt_pkrtz(sv[0], sv[1]));
      pf.u[1] = __builtin_bit_cast(unsigned, __builtin_amdgcn_cvt_pkrtz(sv[2], sv[3]));
      pf.u[2] = __builtin_bit_cast(unsigned, __builtin_amdgcn_cvt_pkrtz(sv[4], sv[5]));
      pf.u[3] = __builtin_bit_cast(unsigned, __builtin_amdgcn_cvt_pkrtz(sv[6], sv[7]));

      // PV (16x16x32, permuted k): o{dt} += Vt'[d][c*32 + 8*g4 ..] * pf
      {
        const int d = 0 * 16 + q16;
        const half8 vf = *(const half8*)(VtB + d * 512 + ((c * 64 + g4 * 16) ^ ((d & 31) << 4)));
        o0 = __builtin_amdgcn_mfma_f32_16x16x32_f16(vf, pf.hh, o0, 0, 0, 0);
      }
      {
        const int d = 1 * 16 + q16;
        const half8 vf = *(const half8*)(VtB + d * 512 + ((c * 64 + g4 * 16) ^ ((d & 31) << 4)));
        o1 = __builtin_amdgcn_mfma_f32_16x16x32_f16(vf, pf.hh, o1, 0, 0, 0);
      }
      {
        const int d = 2 * 16 + q16;
        const half8 vf = *(const half8*)(VtB + d * 512 + ((c * 64 + g4 * 16) ^ ((d & 31) << 4)));
        o2 = __builtin_amdgcn_mfma_f32_16x16x32_f16(vf, pf.hh, o2, 0, 0, 0);
      }
      {
        const int d = 3 * 16 + q16;
        const half8 vf = *(const half8*)(VtB + d * 512 + ((c * 64 + g4 * 16) ^ ((d & 31) << 4)));
        o3 = __builtin_amdgcn_mfma_f32_16x16x32_f16(vf, pf.hh, o3, 0, 0, 0);
      }
    }

    __syncthreads();  // waves done with Kn/Vt; reuse smem for epilogue

    // ---- epilogue: reduce lsum once, stage fp16 in LDS, coalesced stores ----
    lsum += __shfl_xor(lsum, 16);
    lsum += __shfl_xor(lsum, 32);
    char* ob = smem + wv * 2048;  // [16 q][64 d] fp16, byte ^= (q&15)<<3
    const float invl = 1.0f / lsum;
    {
      uint2 w;
      w.x = __builtin_bit_cast(unsigned, __builtin_amdgcn_cvt_pkrtz(o0[0] * invl, o0[1] * invl));
      w.y = __builtin_bit_cast(unsigned, __builtin_amdgcn_cvt_pkrtz(o0[2] * invl, o0[3] * invl));
      *(uint2*)(ob + q16 * 128 + ((0 * 32 + g4 * 8) ^ (q16 << 3))) = w;
      w.x = __builtin_bit_cast(unsigned, __builtin_amdgcn_cvt_pkrtz(o1[0] * invl, o1[1] * invl));
      w.y = __builtin_bit_cast(unsigned, __builtin_amdgcn_cvt_pkrtz(o1[2] * invl, o1[3] * invl));
      *(uint2*)(ob + q16 * 128 + ((1 * 32 + g4 * 8) ^ (q16 << 3))) = w;
      w.x = __builtin_bit_cast(unsigned, __builtin_amdgcn_cvt_pkrtz(o2[0] * invl, o2[1] * invl));
      w.y = __builtin_bit_cast(unsigned, __builtin_amdgcn_cvt_pkrtz(o2[2] * invl, o2[3] * invl));
      *(uint2*)(ob + q16 * 128 + ((2 * 32 + g4 * 8) ^ (q16 << 3))) = w;
      w.x = __builtin_bit_cast(unsigned, __builtin_amdgcn_cvt_pkrtz(o3[0] * invl, o3[1] * invl));
      w.y = __builtin_bit_cast(unsigned, __builtin_amdgcn_cvt_pkrtz(o3[2] * invl, o3[3] * invl));
      *(uint2*)(ob + q16 * 128 + ((3 * 32 + g4 * 8) ^ (q16 << 3))) = w;
    }
    __asm__ __volatile__("s_waitcnt lgkmcnt(0)" ::: "memory");
    __builtin_amdgcn_sched_barrier(0);
    const int qr = lane >> 2;  // 0..15
    const int fc = lane & 3;
#pragma unroll
    for (int it = 0; it < 4; ++it) {
      const int s4 = fc + it * 4;  // float4 slot -> d = s4*4
      union { uint2 u; _Float16 hh[4]; } rd4;
      rd4.u = *(const uint2*)(ob + qr * 128 + ((s4 * 8) ^ (qr << 3)));
      float4 val;
      val.x = (float)rd4.hh[0];
      val.y = (float)rd4.hh[1];
      val.z = (float)rd4.hh[2];
      val.w = (float)rd4.hh[3];
      *(float4*)(out + (((long)(b * 256 + wv * 16 + qr) * 8 + head) * 64 + s4 * 4)) = val;
    }

    __syncthreads();  // epilogue LDS reads done before next tile's converts overwrite
  }
}

extern "C" void kernel_launch(void* const* d_in, const int* in_sizes, int n_in,
                              void* d_out, int out_size, void* d_ws, size_t ws_size,
                              hipStream_t stream) {
  (void)in_sizes; (void)n_in; (void)out_size;
  const float* q = (const float*)d_in[0];
  const float* k = (const float*)d_in[1];
  const float* v = (const float*)d_in[2];
  const float* ls = (const float*)d_in[3];
  const float* bias = (const float*)d_in[4];
  float* out = (float*)d_out;
  const size_t bpBytes = (size_t)8 * 128 * 256 * 4;  // 1 MB
  if (ws_size >= bpBytes) {
    unsigned* biasP = (unsigned*)d_ws;
    bias_pack<<<dim3(8, 8, 8), dim3(32, 8), 0, stream>>>(bias, biasP);
    attn_kernel<true><<<dim3(256), dim3(1024), 0, stream>>>(q, k, v, ls, bias, biasP, out);
  } else {
    attn_kernel<false><<<dim3(256), dim3(1024), 0, stream>>>(q, k, v, ls, bias, nullptr, out);
  }
}